// Round 27
// baseline (146.865 us; speedup 1.0000x reference)
//
#include <hip/hip_runtime.h>
#include <hip/hip_bf16.h>
#include <stdint.h>

typedef __attribute__((ext_vector_type(8))) __bf16 bf16x8;
typedef __attribute__((ext_vector_type(4))) __bf16 bf16x4;
typedef __attribute__((ext_vector_type(4))) float f32x4;
typedef __attribute__((ext_vector_type(16))) float f32x16;

#define MFMA16(a, b, c) __builtin_amdgcn_mfma_f32_16x16x32_bf16((a), (b), (c), 0, 0, 0)
#define MFMA32(a, b, c) __builtin_amdgcn_mfma_f32_32x32x16_bf16((a), (b), (c), 0, 0, 0)

static __device__ __forceinline__ void gload_lds16(const void* g, void* l) {
  __builtin_amdgcn_global_load_lds(
      reinterpret_cast<const __attribute__((address_space(1))) uint32_t*>(
          reinterpret_cast<uintptr_t>(g)),
      reinterpret_cast<__attribute__((address_space(3))) uint32_t*>(
          reinterpret_cast<uintptr_t>(l)),
      16, 0, 0);
}

// ---- fused prep: cvt x->bf16 | transpose wqkv | transpose wo (one dispatch) ----
__global__ __launch_bounds__(256) void prep_fused(
    const float* __restrict__ x, __bf16* __restrict__ xb,
    const float* __restrict__ wqkv, __bf16* __restrict__ wqkvT,
    const float* __restrict__ wo, __bf16* __restrict__ woT) {
  __shared__ float tile[32][33];
  const int bid = (int)blockIdx.x;
  const int tid = threadIdx.x;
  if (bid < 4096) {
    int i = bid * 2048 + tid * 8;
    float4 a = *(const float4*)(x + i);
    float4 b = *(const float4*)(x + i + 4);
    bf16x8 o;
    o[0] = (__bf16)a.x; o[1] = (__bf16)a.y; o[2] = (__bf16)a.z; o[3] = (__bf16)a.w;
    o[4] = (__bf16)b.x; o[5] = (__bf16)b.y; o[6] = (__bf16)b.z; o[7] = (__bf16)b.w;
    *(bf16x8*)(xb + i) = o;
    return;
  }
  const float* in;
  __bf16* out;
  int C, bx, by;
  if (bid < 7168) {
    int t = bid - 4096;
    in = wqkv; out = wqkvT; C = 3072;
    bx = t % 96; by = t / 96;
  } else {
    int t = bid - 7168;
    in = wo; out = woT; C = 1024;
    bx = t & 31; by = t >> 5;
  }
  const int R = 1024;
  int tx = tid & 31, ty = tid >> 5;  // 32 x 8
  int c0 = bx * 32, r0 = by * 32;
#pragma unroll
  for (int i = 0; i < 4; i++)
    tile[ty + i * 8][tx] = in[(size_t)(r0 + ty + i * 8) * C + c0 + tx];
  __syncthreads();
#pragma unroll
  for (int i = 0; i < 4; i++)
    out[(size_t)(c0 + ty + i * 8) * R + r0 + tx] = (__bf16)tile[tx][ty + i * 8];
}

// ------- fat-N GEMM for QKV: [8192,1024] @ [3072,1024]^T, BM=256 BN=384 -------
// 32x32x16 MFMA variant: same FLOPs per K-step in 24 instructions (vs 48
// 16x16x32), halving issue slots + acc-chain depth; 32x32 ceiling is 15%
// higher (2382 vs 2075 TF ubench). Wave = 128x96 -> 12 32x32 tiles, 2 kk
// chains per K-step-32. A/B frag: row/col = lane&31, k = kk*16 + (lane>>5)*8
// -> 16B LDS read at slot (kk*2+hi) ^ ((row>>1)&3) (same swizzle family).
// C/D: col = lane&31, row = (reg&3)+8*(reg>>2)+4*(lane>>5) [m74/m101].
// 2-slot LDS (80KB), two-barrier loop, counted vmcnt(5/0) (round-25 best).
// Grid 256 = 32 tM x 8 tN, single round; xcd=bid%8 owns tM-chunk of 4.
__global__ __launch_bounds__(512) void gemm_fat(
    const __bf16* __restrict__ A, const __bf16* __restrict__ Bt,
    const float* __restrict__ bias,
    __bf16* __restrict__ Qb, __bf16* __restrict__ Kb, __bf16* __restrict__ Vtb) {
  __shared__ __bf16 lA[2][8192];   // [256 rows][32 k]
  __shared__ __bf16 lB[2][12288];  // [384 rows][32 k]
  const int bid0 = (int)blockIdx.x;
  const int tM = (bid0 & 7) * 4 + ((bid0 >> 3) & 3);  // 0..31
  const int tN = bid0 >> 5;                            // 0..7
  const int tid = threadIdx.x;
  const int w = tid >> 6, lane = tid & 63;
  const int wr = w >> 2, wc = w & 3;
  const int l31 = lane & 31, hi = lane >> 5;

  const int srow = tid >> 2;
  const int gcol = ((tid & 3) ^ ((tid >> 3) & 3)) * 8;
  const __bf16* Asrc = A + (size_t)(tM * 256 + srow) * 1024 + gcol;
  const __bf16* Bsrc = Bt + (size_t)(tN * 384 + srow) * 1024 + gcol;

  f32x16 acc[4][3];
#pragma unroll
  for (int m = 0; m < 4; m++)
#pragma unroll
    for (int n = 0; n < 3; n++)
#pragma unroll
      for (int i = 0; i < 16; i++) acc[m][n][i] = 0.f;

  auto stage = [&](int slot, int t) {
    const int k0 = t * 32;
    gload_lds16(Asrc + k0, &lA[slot][tid * 8]);
    gload_lds16(Asrc + 128 * 1024 + k0, &lA[slot][4096 + tid * 8]);
    gload_lds16(Bsrc + k0, &lB[slot][tid * 8]);
    gload_lds16(Bsrc + 128 * 1024 + k0, &lB[slot][4096 + tid * 8]);
    gload_lds16(Bsrc + 256 * 1024 + k0, &lB[slot][8192 + tid * 8]);
  };

  auto compute = [&](int slot) {
    bf16x8 bfr[3][2];
#pragma unroll
    for (int n = 0; n < 3; n++) {
      int row = wc * 96 + n * 32 + l31;
      int sw = (row >> 1) & 3;
#pragma unroll
      for (int kk = 0; kk < 2; kk++) {
        int ls = (kk * 2 + hi) ^ sw;
        bfr[n][kk] = *(const bf16x8*)&lB[slot][row * 32 + ls * 8];
      }
    }
    __builtin_amdgcn_s_setprio(1);
#pragma unroll
    for (int m = 0; m < 4; m++) {
      int row = wr * 128 + m * 32 + l31;
      int sw = (row >> 1) & 3;
#pragma unroll
      for (int kk = 0; kk < 2; kk++) {
        int ls = (kk * 2 + hi) ^ sw;
        bf16x8 a = *(const bf16x8*)&lA[slot][row * 32 + ls * 8];
#pragma unroll
        for (int n = 0; n < 3; n++) acc[m][n] = MFMA32(a, bfr[n][kk], acc[m][n]);
      }
    }
    __builtin_amdgcn_s_setprio(0);
  };

  stage(0, 0);
  int cur = 0;
#pragma unroll 1
  for (int t = 0; t < 32; ++t) {
    __builtin_amdgcn_s_barrier();  // WAR: slot cur^1's readers (t-1) done
    if (t + 1 < 32) {
      stage(cur ^ 1, t + 1);
      asm volatile("s_waitcnt vmcnt(5)" ::: "memory");  // tile t landed
    } else {
      asm volatile("s_waitcnt vmcnt(0)" ::: "memory");
    }
    __builtin_amdgcn_s_barrier();  // tile t visible to all waves
    compute(cur);
    cur ^= 1;
  }

#pragma unroll
  for (int m = 0; m < 4; m++) {
#pragma unroll
    for (int n = 0; n < 3; n++) {
      int col = tN * 384 + wc * 96 + n * 32 + l31;  // 0..3071
      float bv = bias[col];
      int which = col >> 10, rem = col & 1023;
      int hh = rem >> 6, dd = rem & 63;
#pragma unroll
      for (int g = 0; g < 4; g++) {
        int row0 = tM * 256 + wr * 128 + m * 32 + 8 * g + 4 * hi;
        if (which == 2) {
          // V transposed into Vt [bh][64][2048]; 4 consecutive s -> bf16x4
          int bb = row0 >> 11, s0 = row0 & 2047;
          bf16x4 v;
#pragma unroll
          for (int r = 0; r < 4; r++) v[r] = (__bf16)(acc[m][n][g * 4 + r] + bv);
          *(bf16x4*)&Vtb[((size_t)(bb * 16 + hh) * 64 + dd) * 2048 + s0] = v;
        } else {
          __bf16* dst = (which == 0) ? Qb : Kb;
          // fold softmax scale AND log2(e) into Q (attn works in log2 domain)
          float sc = (which == 0) ? 0.18033688f : 1.0f;  // 0.125 * log2(e)
#pragma unroll
          for (int r = 0; r < 4; r++) {
            int row = row0 + r;
            int b = row >> 11, s = row & 2047;
            dst[((size_t)(b * 16 + hh) * 2048 + s) * 64 + dd] =
                (__bf16)((acc[m][n][g * 4 + r] + bv) * sc);
          }
        }
      }
    }
  }
}

// ------- GEMM (pipelined, single-round): out-proj [8192,1024]@[1024,1024]^T -------
// BM=128, BN=256, BK=32, 512 threads (8 waves 2Mx4N), 3-slot LDS rotation
// (72KB), 2-tile prefetch lead, counted vmcnt(3) per K-tile, raw s_barrier.
// 256-block single-round grid. XCD mapping: xcd=bid%8 owns tM-chunk of 8.
template <int EPI, int NPAN>
__global__ __launch_bounds__(512) void gemm_pipe(
    const __bf16* __restrict__ A, const __bf16* __restrict__ Bt,
    const float* __restrict__ bias, float* __restrict__ Cf,
    __bf16* __restrict__ Qb, __bf16* __restrict__ Kb, __bf16* __restrict__ Vtb, int N) {
  __shared__ __bf16 lA[3][128 * 32];
  __shared__ __bf16 lB[3][256 * 32];
  const int bid0 = (int)blockIdx.x;
  const int tM = (bid0 & 7) * 8 + ((bid0 >> 3) & 7);
  const int tN0 = bid0 >> 6;
  const int tid = threadIdx.x;
  const int w = tid >> 6, lane = tid & 63;
  const int wr = w >> 2, wc = w & 3;
  const int lr = lane & 15, lg = lane >> 4;

  const int srow = tid >> 2;
  const int gcol = ((tid & 3) ^ ((tid >> 3) & 3)) * 8;
  const __bf16* Asrc = A + (size_t)(tM * 128 + srow) * 1024 + gcol;
  const int aslot = (lg ^ ((lr >> 1) & 3)) * 8;

#pragma unroll 1
  for (int p = 0; p < NPAN; ++p) {
    const int tN = tN0 + p * 4;
    const __bf16* Bsrc0 = Bt + (size_t)(tN * 256 + srow) * 1024 + gcol;
    const __bf16* Bsrc1 = Bt + (size_t)(tN * 256 + 128 + srow) * 1024 + gcol;

    f32x4 acc[4][4];
#pragma unroll
    for (int m = 0; m < 4; m++)
#pragma unroll
      for (int n = 0; n < 4; n++) acc[m][n] = f32x4{0.f, 0.f, 0.f, 0.f};

    auto stage = [&](int slot, int t) {
      const int k0 = t * 32;
      gload_lds16(Asrc + k0, &lA[slot][tid * 8]);
      gload_lds16(Bsrc0 + k0, &lB[slot][tid * 8]);
      gload_lds16(Bsrc1 + k0, &lB[slot][4096 + tid * 8]);
    };
    auto compute = [&](int slot) {
      bf16x8 a[4], b[4];
#pragma unroll
      for (int m = 0; m < 4; m++) {
        int row = wr * 64 + m * 16 + lr;
        a[m] = *(const bf16x8*)&lA[slot][row * 32 + aslot];
      }
#pragma unroll
      for (int n = 0; n < 4; n++) {
        int row = wc * 64 + n * 16 + lr;
        b[n] = *(const bf16x8*)&lB[slot][row * 32 + aslot];
      }
      __builtin_amdgcn_s_setprio(1);
#pragma unroll
      for (int m = 0; m < 4; m++)
#pragma unroll
        for (int n = 0; n < 4; n++) acc[m][n] = MFMA16(a[m], b[n], acc[m][n]);
      __builtin_amdgcn_s_setprio(0);
    };

    stage(0, 0); stage(1, 1);
    asm volatile("s_waitcnt vmcnt(3)" ::: "memory");
    __builtin_amdgcn_s_barrier();

#pragma unroll 1
    for (int t = 0; t < 30; ++t) {
      stage((t + 2) % 3, t + 2);
      compute(t % 3);
      asm volatile("s_waitcnt vmcnt(3)" ::: "memory");
      __builtin_amdgcn_s_barrier();
    }
    compute(30 % 3);
    asm volatile("s_waitcnt vmcnt(0)" ::: "memory");
    __builtin_amdgcn_s_barrier();
    compute(31 % 3);

#pragma unroll
    for (int m = 0; m < 4; m++) {
#pragma unroll
      for (int n = 0; n < 4; n++) {
        int row0 = tM * 128 + wr * 64 + m * 16 + lg * 4;
        int col = tN * 256 + wc * 64 + n * 16 + lr;
        float bv = bias[col];
        if (EPI == 0) {
          int which = col >> 10, rem = col & 1023;
          int hh = rem >> 6, dd = rem & 63;
          if (which == 2) {
#pragma unroll
            for (int r = 0; r < 4; r++) {
              int row = row0 + r;
              int b = row >> 11, s = row & 2047;
              Vtb[((size_t)(b * 16 + hh) * 64 + dd) * 2048 + s] = (__bf16)(acc[m][n][r] + bv);
            }
          } else {
            __bf16* dst = (which == 0) ? Qb : Kb;
            float sc = (which == 0) ? 0.18033688f : 1.0f;
#pragma unroll
            for (int r = 0; r < 4; r++) {
              int row = row0 + r;
              int b = row >> 11, s = row & 2047;
              dst[((size_t)(b * 16 + hh) * 2048 + s) * 64 + dd] = (__bf16)((acc[m][n][r] + bv) * sc);
            }
          }
        } else {
#pragma unroll
          for (int r = 0; r < 4; r++)
            Cf[(size_t)(row0 + r) * N + col] = acc[m][n][r] + bv;
        }
      }
    }
    if (p + 1 < NPAN) __syncthreads();
  }
}

// ---------------- flash causal attention (8 waves x 16 q-rows) ----------------
// grid: (64 bh, 8 pairs), block 512 (8 waves). Block q-tile 128 (paired with
// 15-pair); wave w owns q rows qbase = qt*128 + w*16 .. +15. 4-slot K/V
// rotation, 2-tile prefetch, counted vmcnt(4/2/0) + raw s_barrier.
// S^T = mfma(K_frag, Q_frag): lane owns q = qbase + lr.
// Scores log2-domain (Q pre-scaled 0.125*log2e). FIXED-SHIFT softmax:
// P = exp2(s-16); masked -1e30 -> 0. l via all-ones MFMA; epilogue 1/l.
__global__ __launch_bounds__(512) void attn_fwd(
    const __bf16* __restrict__ Q, const __bf16* __restrict__ K,
    const __bf16* __restrict__ Vt, __bf16* __restrict__ Y) {
  const int pair = blockIdx.y;
  const int bh = blockIdx.x;
  const int w = threadIdx.x >> 6, lane = threadIdx.x & 63;
  const int lr = lane & 15, lg = lane >> 4;
  const int b = bh >> 4, h = bh & 15;
  const __bf16* Qp = Q + (size_t)bh * 131072;
  const __bf16* Kp = K + (size_t)bh * 131072;
  const __bf16* Vp = Vt + (size_t)bh * 131072;

  __shared__ __bf16 Kl[4][4096];   // [64 kv][64 d], XOR-swizzled 16B slots
  __shared__ __bf16 Vl[4][4096];   // [64 d][64 kv]
  __shared__ __bf16 Pl[8][16 * 64];
  __bf16* Pw = Pl[w];

  bf16x8 kones;
#pragma unroll
  for (int j = 0; j < 8; j++) kones[j] = (__bf16)1.0f;

  auto stage = [&](int slot, int t_) {
    const int kv0_ = t_ * 64;
    int rr = w * 8 + (lane >> 3);
    int sc = ((lane & 7) ^ (rr & 7)) * 8;
    gload_lds16(Kp + (size_t)(kv0_ + rr) * 64 + sc, &Kl[slot][w * 512]);
    gload_lds16(Vp + (size_t)rr * 2048 + kv0_ + sc, &Vl[slot][w * 512]);
  };

  for (int sel = 0; sel < 2; ++sel) {
    const int qt = sel ? (15 - pair) : pair;
    const int qbase = qt * 128 + w * 16;

    bf16x8 aq[2];
#pragma unroll
    for (int c = 0; c < 2; c++)
      aq[c] = *(const bf16x8*)&Qp[(size_t)(qbase + lr) * 64 + c * 32 + lg * 8];

    f32x4 acc_o[4];
    f32x4 acc_l;
#pragma unroll
    for (int dn = 0; dn < 4; dn++) acc_o[dn] = f32x4{0.f, 0.f, 0.f, 0.f};
    acc_l = f32x4{0.f, 0.f, 0.f, 0.f};

    const int nt = 2 * qt + 2;  // >= 2

    stage(0, 0);
    stage(1, 1);

#pragma unroll 1
    for (int t = 0; t < nt; ++t) {
      const int kv0 = t * 64;
      if (t + 2 < nt) stage((t + 2) & 3, t + 2);

      if (t + 2 < nt) {
        asm volatile("s_waitcnt vmcnt(4)" ::: "memory");
      } else if (t + 1 < nt) {
        asm volatile("s_waitcnt vmcnt(2)" ::: "memory");
      } else {
        asm volatile("s_waitcnt vmcnt(0)" ::: "memory");
      }
      __builtin_amdgcn_s_barrier();

      if (kv0 <= qbase + 15) {
        const int cur = t & 3;
        // ---- QK^T swapped: S^T[kv][q] = K @ Q^T (swizzled K reads) ----
        f32x4 s4[4];
#pragma unroll
        for (int n = 0; n < 4; n++) s4[n] = f32x4{0.f, 0.f, 0.f, 0.f};
        __builtin_amdgcn_s_setprio(1);
#pragma unroll
        for (int c = 0; c < 2; c++) {
#pragma unroll
          for (int n = 0; n < 4; n++) {
            int kr = n * 16 + lr;
            int off = kr * 64 + (((c * 64 + lg * 16) ^ ((kr & 7) << 4)) >> 1);
            bf16x8 bk = *(const bf16x8*)&Kl[cur][off];
            s4[n] = MFMA16(bk, aq[c], s4[n]);
          }
        }
        __builtin_amdgcn_s_setprio(0);

        // ---- mask (diag tiles only) + fixed-shift exp2 + packed P write ----
        const bool diag = (kv0 + 63 > qbase);
        const int qrow = qbase + lr;
        if (diag) {
#pragma unroll
          for (int n = 0; n < 4; n++)
#pragma unroll
            for (int r = 0; r < 4; r++)
              if (kv0 + n * 16 + lg * 4 + r > qrow) s4[n][r] = -1e30f;
        }
#pragma unroll
        for (int n = 0; n < 4; n++) {
          bf16x4 pq;
#pragma unroll
          for (int r = 0; r < 4; r++)
            pq[r] = (__bf16)__builtin_amdgcn_exp2f(s4[n][r] - 16.0f);
          int off = lr * 64 + (((n * 32 + lg * 8) ^ ((lr & 7) << 4)) >> 1);
          *(bf16x4*)&Pw[off] = pq;
        }

        // ---- P A-frags from LDS (swizzled reads) ----
        bf16x8 ap[2];
#pragma unroll
        for (int cc = 0; cc < 2; cc++) {
          int off = lr * 64 + (((cc * 64 + lg * 16) ^ ((lr & 7) << 4)) >> 1);
          ap[cc] = *(const bf16x8*)&Pw[off];
        }

        // ---- PV + l-row (ones trick) from LDS V (swizzled reads) ----
        __builtin_amdgcn_s_setprio(1);
#pragma unroll
        for (int cc = 0; cc < 2; cc++)
          acc_l = MFMA16(ap[cc], kones, acc_l);
#pragma unroll
        for (int dn = 0; dn < 4; dn++) {
          int d = dn * 16 + lr;
#pragma unroll
          for (int cc = 0; cc < 2; cc++) {
            int off = d * 64 + (((cc * 64 + lg * 16) ^ ((d & 7) << 4)) >> 1);
            bf16x8 bv = *(const bf16x8*)&Vl[cur][off];
            acc_o[dn] = MFMA16(ap[cc], bv, acc_o[dn]);
          }
        }
        __builtin_amdgcn_s_setprio(0);
      }
    }

    __syncthreads();  // guards slot reuse across sel passes

    // epilogue: acc_l already in O row layout -> no cross-lane reduce needed
#pragma unroll
    for (int r = 0; r < 4; r++) {
      float iv = 1.f / acc_l[r];
      int row = b * 2048 + qbase + lg * 4 + r;
#pragma unroll
      for (int dn = 0; dn < 4; dn++)
        Y[(size_t)row * 1024 + h * 64 + dn * 16 + lr] = (__bf16)(acc_o[dn][r] * iv);
    }
  }
}

extern "C" void kernel_launch(void* const* d_in, const int* in_sizes, int n_in,
                              void* d_out, int out_size, void* d_ws, size_t ws_size,
                              hipStream_t stream) {
  const float* x = (const float*)d_in[0];
  const float* wqkv = (const float*)d_in[1];
  const float* bqkv = (const float*)d_in[2];
  const float* wo = (const float*)d_in[3];
  const float* bo = (const float*)d_in[4];
  float* out = (float*)d_out;

  __bf16* ws = (__bf16*)d_ws;
  __bf16* xb = ws;                      // 8,388,608 elems (reused as Y later)
  __bf16* wqkvT = xb + 8388608;         // 3,145,728
  __bf16* woT = wqkvT + 3145728;        // 1,048,576
  __bf16* Qb = woT + 1048576;           // 8,388,608
  __bf16* Kb = Qb + 8388608;            // 8,388,608
  __bf16* Vtb = Kb + 8388608;           // 8,388,608
  __bf16* Yb = xb;                      // alias: xb dead after QKV gemm

  prep_fused<<<8192, 256, 0, stream>>>(x, xb, wqkv, wqkvT, wo, woT);
  gemm_fat<<<256, 512, 0, stream>>>(xb, wqkvT, bqkv, Qb, Kb, Vtb);
  attn_fwd<<<dim3(64, 8), 512, 0, stream>>>(Qb, Kb, Vtb, Yb);
  gemm_pipe<1, 1><<<256, 512, 0, stream>>>(Yb, woT, bo, out, nullptr, nullptr, nullptr, 1024);
}

// Round 28
// 142.039 us; speedup vs baseline: 1.0340x; 1.0340x over previous
//
#include <hip/hip_runtime.h>
#include <hip/hip_bf16.h>
#include <stdint.h>

typedef __attribute__((ext_vector_type(8))) __bf16 bf16x8;
typedef __attribute__((ext_vector_type(4))) __bf16 bf16x4;
typedef __attribute__((ext_vector_type(4))) float f32x4;

#define MFMA16(a, b, c) __builtin_amdgcn_mfma_f32_16x16x32_bf16((a), (b), (c), 0, 0, 0)

static __device__ __forceinline__ void gload_lds16(const void* g, void* l) {
  __builtin_amdgcn_global_load_lds(
      reinterpret_cast<const __attribute__((address_space(1))) uint32_t*>(
          reinterpret_cast<uintptr_t>(g)),
      reinterpret_cast<__attribute__((address_space(3))) uint32_t*>(
          reinterpret_cast<uintptr_t>(l)),
      16, 0, 0);
}

// ---- fused prep: cvt x->bf16 | transpose wqkv | transpose wo (one dispatch) ----
__global__ __launch_bounds__(256) void prep_fused(
    const float* __restrict__ x, __bf16* __restrict__ xb,
    const float* __restrict__ wqkv, __bf16* __restrict__ wqkvT,
    const float* __restrict__ wo, __bf16* __restrict__ woT) {
  __shared__ float tile[32][33];
  const int bid = (int)blockIdx.x;
  const int tid = threadIdx.x;
  if (bid < 4096) {
    int i = bid * 2048 + tid * 8;
    float4 a = *(const float4*)(x + i);
    float4 b = *(const float4*)(x + i + 4);
    bf16x8 o;
    o[0] = (__bf16)a.x; o[1] = (__bf16)a.y; o[2] = (__bf16)a.z; o[3] = (__bf16)a.w;
    o[4] = (__bf16)b.x; o[5] = (__bf16)b.y; o[6] = (__bf16)b.z; o[7] = (__bf16)b.w;
    *(bf16x8*)(xb + i) = o;
    return;
  }
  const float* in;
  __bf16* out;
  int C, bx, by;
  if (bid < 7168) {
    int t = bid - 4096;
    in = wqkv; out = wqkvT; C = 3072;
    bx = t % 96; by = t / 96;
  } else {
    int t = bid - 7168;
    in = wo; out = woT; C = 1024;
    bx = t & 31; by = t >> 5;
  }
  const int R = 1024;
  int tx = tid & 31, ty = tid >> 5;  // 32 x 8
  int c0 = bx * 32, r0 = by * 32;
#pragma unroll
  for (int i = 0; i < 4; i++)
    tile[ty + i * 8][tx] = in[(size_t)(r0 + ty + i * 8) * C + c0 + tx];
  __syncthreads();
#pragma unroll
  for (int i = 0; i < 4; i++)
    out[(size_t)(c0 + ty + i * 8) * R + r0 + tx] = (__bf16)tile[tx][ty + i * 8];
}

// ------- fat-N GEMM for QKV: [8192,1024] @ [3072,1024]^T, BM=256 BN=384 -------
// Full K per block (no panel loop -> K-lockstep streaming; A+B each read ~once).
// 512 threads (8 waves 2Mx4N: wave = 128 rows x 96 cols -> 48 MFMA/K-step).
// 2-slot LDS (A 16KB + B 24KB per slot = 80KB), two-barrier tile loop,
// counted vmcnt(5) (5 loads/thread/tile). acc[8][6] f32x4.
// Grid 256 = 32 tM x 8 tN, single round; xcd=bid%8 owns tM-chunk of 4.
// Epilogue: Q scatter (+bias, pre-scaled 0.125*log2e), K scatter, V transposed.
__global__ __launch_bounds__(512) void gemm_fat(
    const __bf16* __restrict__ A, const __bf16* __restrict__ Bt,
    const float* __restrict__ bias,
    __bf16* __restrict__ Qb, __bf16* __restrict__ Kb, __bf16* __restrict__ Vtb) {
  __shared__ __bf16 lA[2][8192];   // [256 rows][32 k]
  __shared__ __bf16 lB[2][12288];  // [384 rows][32 k]
  const int bid0 = (int)blockIdx.x;
  const int tM = (bid0 & 7) * 4 + ((bid0 >> 3) & 3);  // 0..31
  const int tN = bid0 >> 5;                            // 0..7
  const int tid = threadIdx.x;
  const int w = tid >> 6, lane = tid & 63;
  const int wr = w >> 2, wc = w & 3;
  const int lr = lane & 15, lg = lane >> 4;

  const int srow = tid >> 2;
  const int gcol = ((tid & 3) ^ ((tid >> 3) & 3)) * 8;
  const __bf16* Asrc = A + (size_t)(tM * 256 + srow) * 1024 + gcol;
  const __bf16* Bsrc = Bt + (size_t)(tN * 384 + srow) * 1024 + gcol;

  f32x4 acc[8][6];
#pragma unroll
  for (int m = 0; m < 8; m++)
#pragma unroll
    for (int n = 0; n < 6; n++) acc[m][n] = f32x4{0.f, 0.f, 0.f, 0.f};

  auto stage = [&](int slot, int t) {
    const int k0 = t * 32;
    gload_lds16(Asrc + k0, &lA[slot][tid * 8]);
    gload_lds16(Asrc + 128 * 1024 + k0, &lA[slot][4096 + tid * 8]);
    gload_lds16(Bsrc + k0, &lB[slot][tid * 8]);
    gload_lds16(Bsrc + 128 * 1024 + k0, &lB[slot][4096 + tid * 8]);
    gload_lds16(Bsrc + 256 * 1024 + k0, &lB[slot][8192 + tid * 8]);
  };

  const int aslot = (lg ^ ((lr >> 1) & 3)) * 8;
  auto compute = [&](int slot) {
    bf16x8 bfr[6];
#pragma unroll
    for (int n = 0; n < 6; n++) {
      int row = wc * 96 + n * 16 + lr;
      bfr[n] = *(const bf16x8*)&lB[slot][row * 32 + aslot];
    }
    __builtin_amdgcn_s_setprio(1);
#pragma unroll
    for (int m = 0; m < 8; m++) {
      int row = wr * 128 + m * 16 + lr;
      bf16x8 a = *(const bf16x8*)&lA[slot][row * 32 + aslot];
#pragma unroll
      for (int n = 0; n < 6; n++) acc[m][n] = MFMA16(a, bfr[n], acc[m][n]);
    }
    __builtin_amdgcn_s_setprio(0);
  };

  stage(0, 0);
  int cur = 0;
#pragma unroll 1
  for (int t = 0; t < 32; ++t) {
    __builtin_amdgcn_s_barrier();  // WAR: slot cur^1's readers (t-1) done
    if (t + 1 < 32) {
      stage(cur ^ 1, t + 1);
      asm volatile("s_waitcnt vmcnt(5)" ::: "memory");  // tile t landed
    } else {
      asm volatile("s_waitcnt vmcnt(0)" ::: "memory");
    }
    __builtin_amdgcn_s_barrier();  // tile t visible to all waves
    compute(cur);
    cur ^= 1;
  }

#pragma unroll
  for (int m = 0; m < 8; m++) {
#pragma unroll
    for (int n = 0; n < 6; n++) {
      int row0 = tM * 256 + wr * 128 + m * 16 + lg * 4;
      int col = tN * 384 + wc * 96 + n * 16 + lr;  // 0..3071
      float bv = bias[col];
      int which = col >> 10, rem = col & 1023;
      int hh = rem >> 6, dd = rem & 63;
      if (which == 2) {
        // V transposed into Vt [bh][64][2048]; 4 consecutive s -> bf16x4
        int bb = row0 >> 11, s0 = row0 & 2047;
        bf16x4 v;
#pragma unroll
        for (int r = 0; r < 4; r++) v[r] = (__bf16)(acc[m][n][r] + bv);
        *(bf16x4*)&Vtb[((size_t)(bb * 16 + hh) * 64 + dd) * 2048 + s0] = v;
      } else {
        __bf16* dst = (which == 0) ? Qb : Kb;
        // fold softmax scale AND log2(e) into Q (attn works in log2 domain)
        float sc = (which == 0) ? 0.18033688f : 1.0f;  // 0.125 * log2(e)
#pragma unroll
        for (int r = 0; r < 4; r++) {
          int row = row0 + r;
          int b = row >> 11, s = row & 2047;
          dst[((size_t)(b * 16 + hh) * 2048 + s) * 64 + dd] = (__bf16)((acc[m][n][r] + bv) * sc);
        }
      }
    }
  }
}

// ------- GEMM (pipelined, single-round): out-proj [8192,1024]@[1024,1024]^T -------
// BM=128, BN=256, BK=32, 512 threads (8 waves 2Mx4N), 3-slot LDS rotation
// (72KB), 2-tile prefetch lead, counted vmcnt(3) per K-tile, raw s_barrier.
// 256-block single-round grid. XCD mapping: xcd=bid%8 owns tM-chunk of 8.
template <int EPI, int NPAN>
__global__ __launch_bounds__(512) void gemm_pipe(
    const __bf16* __restrict__ A, const __bf16* __restrict__ Bt,
    const float* __restrict__ bias, float* __restrict__ Cf,
    __bf16* __restrict__ Qb, __bf16* __restrict__ Kb, __bf16* __restrict__ Vtb, int N) {
  __shared__ __bf16 lA[3][128 * 32];
  __shared__ __bf16 lB[3][256 * 32];
  const int bid0 = (int)blockIdx.x;
  const int tM = (bid0 & 7) * 8 + ((bid0 >> 3) & 7);
  const int tN0 = bid0 >> 6;
  const int tid = threadIdx.x;
  const int w = tid >> 6, lane = tid & 63;
  const int wr = w >> 2, wc = w & 3;
  const int lr = lane & 15, lg = lane >> 4;

  const int srow = tid >> 2;
  const int gcol = ((tid & 3) ^ ((tid >> 3) & 3)) * 8;
  const __bf16* Asrc = A + (size_t)(tM * 128 + srow) * 1024 + gcol;
  const int aslot = (lg ^ ((lr >> 1) & 3)) * 8;

#pragma unroll 1
  for (int p = 0; p < NPAN; ++p) {
    const int tN = tN0 + p * 4;
    const __bf16* Bsrc0 = Bt + (size_t)(tN * 256 + srow) * 1024 + gcol;
    const __bf16* Bsrc1 = Bt + (size_t)(tN * 256 + 128 + srow) * 1024 + gcol;

    f32x4 acc[4][4];
#pragma unroll
    for (int m = 0; m < 4; m++)
#pragma unroll
      for (int n = 0; n < 4; n++) acc[m][n] = f32x4{0.f, 0.f, 0.f, 0.f};

    auto stage = [&](int slot, int t) {
      const int k0 = t * 32;
      gload_lds16(Asrc + k0, &lA[slot][tid * 8]);
      gload_lds16(Bsrc0 + k0, &lB[slot][tid * 8]);
      gload_lds16(Bsrc1 + k0, &lB[slot][4096 + tid * 8]);
    };
    auto compute = [&](int slot) {
      bf16x8 a[4], b[4];
#pragma unroll
      for (int m = 0; m < 4; m++) {
        int row = wr * 64 + m * 16 + lr;
        a[m] = *(const bf16x8*)&lA[slot][row * 32 + aslot];
      }
#pragma unroll
      for (int n = 0; n < 4; n++) {
        int row = wc * 64 + n * 16 + lr;
        b[n] = *(const bf16x8*)&lB[slot][row * 32 + aslot];
      }
      __builtin_amdgcn_s_setprio(1);
#pragma unroll
      for (int m = 0; m < 4; m++)
#pragma unroll
        for (int n = 0; n < 4; n++) acc[m][n] = MFMA16(a[m], b[n], acc[m][n]);
      __builtin_amdgcn_s_setprio(0);
    };

    stage(0, 0); stage(1, 1);
    asm volatile("s_waitcnt vmcnt(3)" ::: "memory");
    __builtin_amdgcn_s_barrier();

#pragma unroll 1
    for (int t = 0; t < 30; ++t) {
      stage((t + 2) % 3, t + 2);
      compute(t % 3);
      asm volatile("s_waitcnt vmcnt(3)" ::: "memory");
      __builtin_amdgcn_s_barrier();
    }
    compute(30 % 3);
    asm volatile("s_waitcnt vmcnt(0)" ::: "memory");
    __builtin_amdgcn_s_barrier();
    compute(31 % 3);

#pragma unroll
    for (int m = 0; m < 4; m++) {
#pragma unroll
      for (int n = 0; n < 4; n++) {
        int row0 = tM * 128 + wr * 64 + m * 16 + lg * 4;
        int col = tN * 256 + wc * 64 + n * 16 + lr;
        float bv = bias[col];
        if (EPI == 0) {
          int which = col >> 10, rem = col & 1023;
          int hh = rem >> 6, dd = rem & 63;
          if (which == 2) {
#pragma unroll
            for (int r = 0; r < 4; r++) {
              int row = row0 + r;
              int b = row >> 11, s = row & 2047;
              Vtb[((size_t)(b * 16 + hh) * 64 + dd) * 2048 + s] = (__bf16)(acc[m][n][r] + bv);
            }
          } else {
            __bf16* dst = (which == 0) ? Qb : Kb;
            float sc = (which == 0) ? 0.18033688f : 1.0f;
#pragma unroll
            for (int r = 0; r < 4; r++) {
              int row = row0 + r;
              int b = row >> 11, s = row & 2047;
              dst[((size_t)(b * 16 + hh) * 2048 + s) * 64 + dd] = (__bf16)((acc[m][n][r] + bv) * sc);
            }
          }
        } else {
#pragma unroll
          for (int r = 0; r < 4; r++)
            Cf[(size_t)(row0 + r) * N + col] = acc[m][n][r] + bv;
        }
      }
    }
    if (p + 1 < NPAN) __syncthreads();
  }
}

// ---------------- flash causal attention (8 waves x 16 q-rows) ----------------
// grid: (64 bh, 8 pairs), block 512 (8 waves). Block q-tile 128 (paired with
// 15-pair); wave w owns q rows qbase = qt*128 + w*16 .. +15. 4-slot K/V
// rotation, 2-tile prefetch, counted vmcnt(4/2/0) + raw s_barrier.
// S^T = mfma(K_frag, Q_frag): lane owns q = qbase + lr.
// Scores log2-domain (Q pre-scaled 0.125*log2e). FIXED-SHIFT softmax:
// P = exp2(s-16); masked -1e30 -> 0. l via all-ones MFMA; epilogue 1/l.
__global__ __launch_bounds__(512) void attn_fwd(
    const __bf16* __restrict__ Q, const __bf16* __restrict__ K,
    const __bf16* __restrict__ Vt, __bf16* __restrict__ Y) {
  const int pair = blockIdx.y;
  const int bh = blockIdx.x;
  const int w = threadIdx.x >> 6, lane = threadIdx.x & 63;
  const int lr = lane & 15, lg = lane >> 4;
  const int b = bh >> 4, h = bh & 15;
  const __bf16* Qp = Q + (size_t)bh * 131072;
  const __bf16* Kp = K + (size_t)bh * 131072;
  const __bf16* Vp = Vt + (size_t)bh * 131072;

  __shared__ __bf16 Kl[4][4096];   // [64 kv][64 d], XOR-swizzled 16B slots
  __shared__ __bf16 Vl[4][4096];   // [64 d][64 kv]
  __shared__ __bf16 Pl[8][16 * 64];
  __bf16* Pw = Pl[w];

  bf16x8 kones;
#pragma unroll
  for (int j = 0; j < 8; j++) kones[j] = (__bf16)1.0f;

  auto stage = [&](int slot, int t_) {
    const int kv0_ = t_ * 64;
    int rr = w * 8 + (lane >> 3);
    int sc = ((lane & 7) ^ (rr & 7)) * 8;
    gload_lds16(Kp + (size_t)(kv0_ + rr) * 64 + sc, &Kl[slot][w * 512]);
    gload_lds16(Vp + (size_t)rr * 2048 + kv0_ + sc, &Vl[slot][w * 512]);
  };

  for (int sel = 0; sel < 2; ++sel) {
    const int qt = sel ? (15 - pair) : pair;
    const int qbase = qt * 128 + w * 16;

    bf16x8 aq[2];
#pragma unroll
    for (int c = 0; c < 2; c++)
      aq[c] = *(const bf16x8*)&Qp[(size_t)(qbase + lr) * 64 + c * 32 + lg * 8];

    f32x4 acc_o[4];
    f32x4 acc_l;
#pragma unroll
    for (int dn = 0; dn < 4; dn++) acc_o[dn] = f32x4{0.f, 0.f, 0.f, 0.f};
    acc_l = f32x4{0.f, 0.f, 0.f, 0.f};

    const int nt = 2 * qt + 2;  // >= 2

    stage(0, 0);
    stage(1, 1);

#pragma unroll 1
    for (int t = 0; t < nt; ++t) {
      const int kv0 = t * 64;
      if (t + 2 < nt) stage((t + 2) & 3, t + 2);

      if (t + 2 < nt) {
        asm volatile("s_waitcnt vmcnt(4)" ::: "memory");
      } else if (t + 1 < nt) {
        asm volatile("s_waitcnt vmcnt(2)" ::: "memory");
      } else {
        asm volatile("s_waitcnt vmcnt(0)" ::: "memory");
      }
      __builtin_amdgcn_s_barrier();

      if (kv0 <= qbase + 15) {
        const int cur = t & 3;
        // ---- QK^T swapped: S^T[kv][q] = K @ Q^T (swizzled K reads) ----
        f32x4 s4[4];
#pragma unroll
        for (int n = 0; n < 4; n++) s4[n] = f32x4{0.f, 0.f, 0.f, 0.f};
        __builtin_amdgcn_s_setprio(1);
#pragma unroll
        for (int c = 0; c < 2; c++) {
#pragma unroll
          for (int n = 0; n < 4; n++) {
            int kr = n * 16 + lr;
            int off = kr * 64 + (((c * 64 + lg * 16) ^ ((kr & 7) << 4)) >> 1);
            bf16x8 bk = *(const bf16x8*)&Kl[cur][off];
            s4[n] = MFMA16(bk, aq[c], s4[n]);
          }
        }
        __builtin_amdgcn_s_setprio(0);

        // ---- mask (diag tiles only) + fixed-shift exp2 + packed P write ----
        const bool diag = (kv0 + 63 > qbase);
        const int qrow = qbase + lr;
        if (diag) {
#pragma unroll
          for (int n = 0; n < 4; n++)
#pragma unroll
            for (int r = 0; r < 4; r++)
              if (kv0 + n * 16 + lg * 4 + r > qrow) s4[n][r] = -1e30f;
        }
#pragma unroll
        for (int n = 0; n < 4; n++) {
          bf16x4 pq;
#pragma unroll
          for (int r = 0; r < 4; r++)
            pq[r] = (__bf16)__builtin_amdgcn_exp2f(s4[n][r] - 16.0f);
          int off = lr * 64 + (((n * 32 + lg * 8) ^ ((lr & 7) << 4)) >> 1);
          *(bf16x4*)&Pw[off] = pq;
        }

        // ---- P A-frags from LDS (swizzled reads) ----
        bf16x8 ap[2];
#pragma unroll
        for (int cc = 0; cc < 2; cc++) {
          int off = lr * 64 + (((cc * 64 + lg * 16) ^ ((lr & 7) << 4)) >> 1);
          ap[cc] = *(const bf16x8*)&Pw[off];
        }

        // ---- PV + l-row (ones trick) from LDS V (swizzled reads) ----
        __builtin_amdgcn_s_setprio(1);
#pragma unroll
        for (int cc = 0; cc < 2; cc++)
          acc_l = MFMA16(ap[cc], kones, acc_l);
#pragma unroll
        for (int dn = 0; dn < 4; dn++) {
          int d = dn * 16 + lr;
#pragma unroll
          for (int cc = 0; cc < 2; cc++) {
            int off = d * 64 + (((cc * 64 + lg * 16) ^ ((d & 7) << 4)) >> 1);
            bf16x8 bv = *(const bf16x8*)&Vl[cur][off];
            acc_o[dn] = MFMA16(ap[cc], bv, acc_o[dn]);
          }
        }
        __builtin_amdgcn_s_setprio(0);
      }
    }

    __syncthreads();  // guards slot reuse across sel passes

    // epilogue: acc_l already in O row layout -> no cross-lane reduce needed
#pragma unroll
    for (int r = 0; r < 4; r++) {
      float iv = 1.f / acc_l[r];
      int row = b * 2048 + qbase + lg * 4 + r;
#pragma unroll
      for (int dn = 0; dn < 4; dn++)
        Y[(size_t)row * 1024 + h * 64 + dn * 16 + lr] = (__bf16)(acc_o[dn][r] * iv);
    }
  }
}

extern "C" void kernel_launch(void* const* d_in, const int* in_sizes, int n_in,
                              void* d_out, int out_size, void* d_ws, size_t ws_size,
                              hipStream_t stream) {
  const float* x = (const float*)d_in[0];
  const float* wqkv = (const float*)d_in[1];
  const float* bqkv = (const float*)d_in[2];
  const float* wo = (const float*)d_in[3];
  const float* bo = (const float*)d_in[4];
  float* out = (float*)d_out;

  __bf16* ws = (__bf16*)d_ws;
  __bf16* xb = ws;                      // 8,388,608 elems (reused as Y later)
  __bf16* wqkvT = xb + 8388608;         // 3,145,728
  __bf16* woT = wqkvT + 3145728;        // 1,048,576
  __bf16* Qb = woT + 1048576;           // 8,388,608
  __bf16* Kb = Qb + 8388608;            // 8,388,608
  __bf16* Vtb = Kb + 8388608;           // 8,388,608
  __bf16* Yb = xb;                      // alias: xb dead after QKV gemm

  prep_fused<<<8192, 256, 0, stream>>>(x, xb, wqkv, wqkvT, wo, woT);
  gemm_fat<<<256, 512, 0, stream>>>(xb, wqkvT, bqkv, Qb, Kb, Vtb);
  attn_fwd<<<dim3(64, 8), 512, 0, stream>>>(Qb, Kb, Vtb, Yb);
  gemm_pipe<1, 1><<<256, 512, 0, stream>>>(Yb, woT, bo, out, nullptr, nullptr, nullptr, 1024);
}